// Round 11
// baseline (251.132 us; speedup 1.0000x reference)
//
#include <hip/hip_runtime.h>
#include <math.h>

// ===========================================================================
// Shared epilogue: 3x3 symmetric Jacobi eigensolve (double) + output writes.
// acc layout (13 floats): [0..2]=sum f  [3..5]=sum r x f
//                         [6..11]=sum rr^T (xx,yy,zz,xy,xz,yz)  [12]=count
// ===========================================================================
__device__ __forceinline__ void frag_epilogue(
    const float* a, int f, int n_frag, const int* __restrict__ frag_sizes,
    float* __restrict__ out)
{
    float cntf  = a[12];
    float denom = fmaxf(cntf, 1.0f);
    float vfx = a[0] / denom, vfy = a[1] / denom, vfz = a[2] / denom;

    double tq0 = (double)a[3], tq1 = (double)a[4], tq2 = (double)a[5];
    double Mxx = (double)a[6], Myy = (double)a[7], Mzz = (double)a[8];
    double Mxy = (double)a[9], Mxz = (double)a[10], Myz = (double)a[11];
    double tr = Mxx + Myy + Mzz;

    double A[3][3] = {
        { tr - Mxx, -Mxy,     -Mxz     },
        { -Mxy,     tr - Myy, -Myz     },
        { -Mxz,     -Myz,     tr - Mzz }
    };
    double V[3][3] = {{1,0,0},{0,1,0},{0,0,1}};

    for (int sweep = 0; sweep < 6; ++sweep) {
        for (int pq = 0; pq < 3; ++pq) {
            int p = (pq == 2) ? 1 : 0;
            int q = (pq == 0) ? 1 : 2;
            double apq = A[p][q];
            if (fabs(apq) <= 1e-14 * (fabs(A[p][p]) + fabs(A[q][q])) ||
                fabs(apq) < 1e-300) continue;
            double theta = (A[q][q] - A[p][p]) / (2.0 * apq);
            double tt;
            if (fabs(theta) > 1e100) tt = 1.0 / (2.0 * theta);
            else tt = copysign(1.0, theta) / (fabs(theta) + sqrt(theta * theta + 1.0));
            double c = 1.0 / sqrt(tt * tt + 1.0);
            double s = tt * c;
            double app = A[p][p], aqq = A[q][q];
            A[p][p] = app - tt * apq;
            A[q][q] = aqq + tt * apq;
            A[p][q] = 0.0; A[q][p] = 0.0;
            int r = 3 - p - q;
            double arp = A[r][p], arq = A[r][q];
            A[r][p] = c * arp - s * arq; A[p][r] = A[r][p];
            A[r][q] = s * arp + c * arq; A[q][r] = A[r][q];
            for (int i2 = 0; i2 < 3; ++i2) {
                double vip = V[i2][p], viq = V[i2][q];
                V[i2][p] = c * vip - s * viq;
                V[i2][q] = s * vip + c * viq;
            }
        }
    }

    double lam0 = A[0][0], lam1 = A[1][1], lam2 = A[2][2];
    double maxeig = fmax(fmax(fmax(lam0, lam1), lam2), 1e-8);
    double thr = 0.01 * maxeig;
    bool small_frag = (frag_sizes[f] <= 1);
    double o0 = (!small_frag && lam0 > thr) ? 1.0 : 0.0;
    double o1 = (!small_frag && lam1 > thr) ? 1.0 : 0.0;
    double o2 = (!small_frag && lam2 > thr) ? 1.0 : 0.0;

    double te0 = V[0][0]*tq0 + V[1][0]*tq1 + V[2][0]*tq2;
    double te1 = V[0][1]*tq0 + V[1][1]*tq1 + V[2][1]*tq2;
    double te2 = V[0][2]*tq0 + V[1][2]*tq1 + V[2][2]*tq2;
    double we0 = te0 / fmax(lam0, 1e-6) * o0;
    double we1 = te1 / fmax(lam1, 1e-6) * o1;
    double we2 = te2 / fmax(lam2, 1e-6) * o2;
    double w0 = V[0][0]*we0 + V[0][1]*we1 + V[0][2]*we2;
    double w1 = V[1][0]*we0 + V[1][1]*we1 + V[1][2]*we2;
    double w2 = V[2][0]*we0 + V[2][1]*we1 + V[2][2]*we2;

    size_t F = (size_t)n_frag;
    out[(size_t)f*3 + 0] = vfx;
    out[(size_t)f*3 + 1] = vfy;
    out[(size_t)f*3 + 2] = vfz;
    out[F*3 + (size_t)f*3 + 0] = (float)w0;
    out[F*3 + (size_t)f*3 + 1] = (float)w1;
    out[F*3 + (size_t)f*3 + 2] = (float)w2;

    float* P = out + F*6 + (size_t)f*9;
    #pragma unroll
    for (int i2 = 0; i2 < 3; ++i2)
        #pragma unroll
        for (int k = 0; k < 3; ++k)
            P[i2*3 + k] = (float)(V[i2][0]*o0*V[k][0] + V[i2][1]*o1*V[k][1]
                                  + V[i2][2]*o2*V[k][2]);
}

// ===========================================================================
// FAST PATH (round 18): 26-byte records. Rounds 7+10 falsified run-length
// (>128B) and occupancy as scatter levers; write amplification is only 3%,
// so scatter sits at the DRAM scattered-line byte-rate floor (~2.4 TB/s).
// Only remaining lever: fewer bytes. Record = (r,f) 6 floats (24 B, r=pos-T
// computed in scatter; identical f32 math as before) + separate u16 lf
// stream. Write traffic 131->~105 MB; sort_reduce reads 128->~104 MB and
// recs footprint 144->117 MB (better L3 retention). Both kernels 512-thr.
// ===========================================================================
#define NBK  512             // bucket slots (used: nbk = ceil(F/400) = 500)
#define FPB  400             // fragments per bucket (500*400 = 200,000 exact)
#define BCAP 9000            // record capacity per bucket region
#define CAP2 1024            // LDS sort chunk capacity (records) in sort_reduce
#define MAXPT 2              // CAP2 / 512
#define TILE 16
#define APB  (256 * TILE)    // 4096 atoms per scatter block
#define SCHUNK 2048          // scatter LDS-sort chunk (atoms)
#define CPT    4             // SCHUNK / 512
#define RECMAX (500u * BCAP) // total record slots (nbk * BCAP)

__global__ __launch_bounds__(256) void init_cursors(
    unsigned* __restrict__ cursor, int nbk)
{
    int b = blockIdx.x * 256 + threadIdx.x;
    if (b <= nbk) cursor[b] = (unsigned)b * BCAP;
}

// Scatter with per-chunk LDS counting sort -> linear (segment-coalesced)
// global write-out into atomically reserved per-bucket windows.
// Record stream: rec6[addr*6..+5] = (rx,ry,rz,fx,fy,fz); lfs[addr] = lf.
__global__ __launch_bounds__(512) void scatter_atoms(
    const float* __restrict__ f_atom,
    const float* __restrict__ atom_pos,
    const int*   __restrict__ frag_id,
    const float* __restrict__ T_frag,
    unsigned*    __restrict__ cursor,
    float*       __restrict__ rec6,
    unsigned short* __restrict__ lfs,
    int n_atom)
{
    __shared__ float    srt[SCHUNK * 7];  // 57,344 B staging (6 data + packed ids)
    __shared__ unsigned hist[NBK];        // per-chunk bucket counts
    __shared__ unsigned cbase[NBK];       // per-chunk exclusive bucket offsets
    __shared__ unsigned obase[NBK];       // reserved global window per bucket
    __shared__ unsigned wsum[4];
    int t = threadIdx.x;
    int lane = t & 63, w = t >> 6;

    for (int b = t; b < NBK; b += 512) hist[b] = 0;
    __syncthreads();

    const int4*   fid4 = (const int4*)frag_id;
    const float4* pos4 = (const float4*)atom_pos;
    const float4* ff4  = (const float4*)f_atom;
    int bs = blockIdx.x * APB;

    for (int c = 0; c < APB / SCHUNK; ++c) {
        int cs = bs + c * SCHUNK;
        int mchunk = n_atom - cs;
        if (mchunk > SCHUNK) mchunk = SCHUNK;
        if (mchunk < 0) mchunk = 0;

        // --- load + rank (4 atoms/thread = 1 int4 group); r = pos - T ---
        int      bkv[CPT], lfv[CPT];
        unsigned rk[CPT];
        float ax[CPT], ay[CPT], az[CPT], gx[CPT], gy[CPT], gz[CPT];
        {
            int i4 = (cs >> 2) + t;
            if (4 * i4 < n_atom) {
                int4 v = fid4[i4];
                float4 p0 = pos4[3*(size_t)i4+0], p1 = pos4[3*(size_t)i4+1], p2 = pos4[3*(size_t)i4+2];
                float4 g0 = ff4[3*(size_t)i4+0],  g1 = ff4[3*(size_t)i4+1],  g2 = ff4[3*(size_t)i4+2];
                int   fid_[4] = {v.x, v.y, v.z, v.w};
                float px_[4] = {p0.x, p0.w, p1.z, p2.y};
                float py_[4] = {p0.y, p1.x, p1.w, p2.z};
                float pz_[4] = {p0.z, p1.y, p2.x, p2.w};
                float gx_[4] = {g0.x, g0.w, g1.z, g2.y};
                float gy_[4] = {g0.y, g1.x, g1.w, g2.z};
                float gz_[4] = {g0.z, g1.y, g2.x, g2.w};
                #pragma unroll
                for (int cc = 0; cc < 4; ++cc) {
                    int fid = fid_[cc];
                    int bk = fid / FPB;
                    bkv[cc] = bk;
                    lfv[cc] = fid - bk * FPB;
                    rk[cc]  = atomicAdd(&hist[bk], 1u);
                    float tx = T_frag[3*fid+0], ty = T_frag[3*fid+1], tz = T_frag[3*fid+2];
                    ax[cc] = px_[cc] - tx; ay[cc] = py_[cc] - ty; az[cc] = pz_[cc] - tz;
                    gx[cc] = gx_[cc]; gy[cc] = gy_[cc]; gz[cc] = gz_[cc];
                }
            } else {
                #pragma unroll
                for (int cc = 0; cc < 4; ++cc) bkv[cc] = -1;
            }
        }
        __syncthreads();

        // --- reserve global windows (1 atomicAdd per nonzero bucket) ---
        for (int b = t; b < NBK; b += 512) {
            unsigned cnt = hist[b];
            obase[b] = cnt ? atomicAdd(&cursor[b], cnt) : 0u;
        }

        // --- exclusive scan of hist[512] via wave shfl (256 pairs, waves 0-3) ---
        unsigned pv = 0, incl = 0;
        if (t < 256) {
            pv = hist[2*t] + hist[2*t + 1];
            incl = pv;
        }
        if (w < 4) {
            #pragma unroll
            for (int st = 1; st < 64; st <<= 1) {
                unsigned v = __shfl_up(incl, (unsigned)st, 64);
                if (lane >= st) incl += v;
            }
            if (lane == 63) wsum[w] = incl;
        }
        __syncthreads();
        if (t == 0) {
            unsigned cum = 0;
            #pragma unroll
            for (int k = 0; k < 4; ++k) { unsigned v = wsum[k]; wsum[k] = cum; cum += v; }
        }
        __syncthreads();
        if (t < 256) {
            unsigned excl = incl - pv + wsum[w];
            cbase[2*t]     = excl;
            cbase[2*t + 1] = excl + hist[2*t];
        }
        __syncthreads();

        // --- scatter into LDS in bucket-sorted order ---
        #pragma unroll
        for (int k = 0; k < CPT; ++k) {
            if (bkv[k] >= 0) {
                unsigned p = (cbase[bkv[k]] + rk[k]) * 7u;
                srt[p+0] = ax[k]; srt[p+1] = ay[k]; srt[p+2] = az[k];
                srt[p+3] = gx[k]; srt[p+4] = gy[k]; srt[p+5] = gz[k];
                srt[p+6] = __int_as_float(lfv[k] | (bkv[k] << 16));
            }
        }
        __syncthreads();

        // --- linear write-out: 24 B record as 3x float2 (8-B aligned) + u16 lf ---
        #pragma unroll
        for (int k = 0; k < CPT; ++k) {
            int j = t + k * 512;
            if (j < mchunk) {
                const float* d = &srt[(unsigned)j * 7u];
                int pk = __float_as_int(d[6]);
                int lf = pk & 0xFFFF;
                int bk = pk >> 16;
                unsigned addr = obase[bk] + (unsigned)j - cbase[bk];
                if (addr < RECMAX) {   // OOB guard: cannot fault even on overflow
                    float2* r2 = (float2*)&rec6[(size_t)addr * 6u];
                    r2[0] = make_float2(d[0], d[1]);
                    r2[1] = make_float2(d[2], d[3]);
                    r2[2] = make_float2(d[4], d[5]);
                    lfs[addr] = (unsigned short)lf;
                }
            }
        }
        __syncthreads();

        // --- zero hist for next chunk ---
        for (int b = t; b < NBK; b += 512) hist[b] = 0;
        __syncthreads();
    }
}

// Counting-sort reduce: 512 threads, CAP2=1024, wave-shfl scan,
// 1 thread per fragment walk. 1 LDS atomic per record (rank only).
// Records already hold r = pos - T (no T lookup, no subtraction here).
__global__ __launch_bounds__(512) void sort_reduce(
    const float*    __restrict__ rec6,
    const unsigned short* __restrict__ lfs,
    const unsigned* __restrict__ cursor,
    const int*      __restrict__ frag_sizes,
    float*          __restrict__ out,
    int n_frag)
{
    __shared__ float    srt[CAP2 * 7];   // 28,672 B (stride 7 for bank spread)
    __shared__ unsigned hist[FPB];       // 1600 B
    __shared__ unsigned cbase[FPB];      // 1600 B
    __shared__ unsigned wsum[8];

    int b = blockIdx.x, t = threadIdx.x;
    int lane = t & 63, w = t >> 6;
    int frag0 = b * FPB;
    int nf = n_frag - frag0;
    if (nf > FPB) nf = FPB;

    unsigned start = (unsigned)b * BCAP;
    unsigned end   = cursor[b];
    // clamp against pathological overflow (defensive, matches scatter guard)
    unsigned cap = (unsigned)(b + 1) * BCAP;
    if (end > cap) end = cap;

    bool own = (t < nf);
    float s[12];
    #pragma unroll
    for (int k = 0; k < 12; ++k) s[k] = 0.0f;
    unsigned fragcnt = 0;

    for (unsigned c0 = start; c0 < end; c0 += CAP2) {
        unsigned m = end - c0;
        if (m > CAP2) m = CAP2;

        for (int k = t; k < FPB; k += 512) hist[k] = 0;
        __syncthreads();

        // --- load + rank (3x float2 + u16 per record, dense coalescing) ---
        float2 ra[MAXPT], rb[MAXPT], rc[MAXPT];
        int rlf[MAXPT];
        unsigned rrk[MAXPT];
        #pragma unroll
        for (int k = 0; k < MAXPT; ++k) {
            unsigned i = (unsigned)t + (unsigned)k * 512u;
            rlf[k] = -1;
            if (i < m) {
                const float2* r2 = (const float2*)&rec6[(size_t)(c0 + i) * 6u];
                ra[k] = r2[0];
                rb[k] = r2[1];
                rc[k] = r2[2];
                int lf = (int)lfs[c0 + i];
                rlf[k] = lf;
                rrk[k] = atomicAdd(&hist[lf], 1u);
            }
        }
        __syncthreads();

        // --- exclusive scan of hist[400] via wave shfl (pairs in waves 0..3) ---
        unsigned p = 0;
        if (t < FPB / 2) p = hist[2*t] + hist[2*t + 1];
        unsigned incl = p;
        if (w < 4) {
            #pragma unroll
            for (int st = 1; st < 64; st <<= 1) {
                unsigned v = __shfl_up(incl, (unsigned)st, 64);
                if (lane >= st) incl += v;
            }
            if (lane == 63) wsum[w] = incl;
        }
        __syncthreads();
        if (t == 0) {
            unsigned c = 0;
            #pragma unroll
            for (int k = 0; k < 4; ++k) { unsigned v = wsum[k]; wsum[k] = c; c += v; }
        }
        __syncthreads();
        if (t < FPB / 2) {
            unsigned excl = incl - p + wsum[w];
            cbase[2*t]     = excl;
            cbase[2*t + 1] = excl + hist[2*t];
        }
        __syncthreads();

        // --- scatter into LDS in fragment-sorted order (stride 7) ---
        #pragma unroll
        for (int k = 0; k < MAXPT; ++k) {
            if (rlf[k] >= 0) {
                unsigned q = (cbase[rlf[k]] + rrk[k]) * 7u;
                srt[q + 0] = ra[k].x; srt[q + 1] = ra[k].y; srt[q + 2] = rb[k].x;
                srt[q + 3] = rb[k].y; srt[q + 4] = rc[k].x; srt[q + 5] = rc[k].y;
            }
        }
        __syncthreads();

        // --- per-fragment serial walk (1 thread/frag); r precomputed ---
        if (own) {
            unsigned cb = cbase[t], cnt = hist[t];
            fragcnt += cnt;
            for (unsigned k = 0; k < cnt; ++k) {
                const float* d = &srt[(cb + k) * 7u];
                float rx = d[0], ry = d[1], rz = d[2];
                float Fx = d[3], Fy = d[4], Fz = d[5];
                s[0] += Fx; s[1] += Fy; s[2] += Fz;
                s[3] += ry*Fz - rz*Fy;
                s[4] += rz*Fx - rx*Fz;
                s[5] += rx*Fy - ry*Fx;
                s[6] += rx*rx; s[7] += ry*ry; s[8] += rz*rz;
                s[9] += rx*ry; s[10] += rx*rz; s[11] += ry*rz;
            }
        }
        __syncthreads();
    }

    if (own) {
        float a[13];
        #pragma unroll
        for (int k = 0; k < 12; ++k) a[k] = s[k];
        a[12] = (float)fragcnt;
        frag_epilogue(a, frag0 + t, n_frag, frag_sizes, out);
    }
}

// ===========================================================================
// FALLBACK: direct global f32 atomics (round-1, correctness-safe, any ws)
// ===========================================================================
#define NACC 16

__global__ __launch_bounds__(256) void atom_scatter_fb(
    const float* __restrict__ f_atom, const float* __restrict__ atom_pos,
    const float* __restrict__ T_frag, const int* __restrict__ frag_id,
    float* __restrict__ acc, int n_atom)
{
    int i = blockIdx.x * blockDim.x + threadIdx.x;
    if (i >= n_atom) return;
    int fid = frag_id[i];
    float fx = f_atom[3*i+0], fy = f_atom[3*i+1], fz = f_atom[3*i+2];
    float px = atom_pos[3*i+0], py = atom_pos[3*i+1], pz = atom_pos[3*i+2];
    float rx = px - T_frag[3*fid+0], ry = py - T_frag[3*fid+1], rz = pz - T_frag[3*fid+2];
    float cx = ry*fz - rz*fy, cy = rz*fx - rx*fz, cz = rx*fy - ry*fx;
    float* a = acc + (size_t)fid * NACC;
    atomicAdd(a+0, fx);    atomicAdd(a+1, fy);    atomicAdd(a+2, fz);
    atomicAdd(a+3, cx);    atomicAdd(a+4, cy);    atomicAdd(a+5, cz);
    atomicAdd(a+6, rx*rx); atomicAdd(a+7, ry*ry); atomicAdd(a+8, rz*rz);
    atomicAdd(a+9, rx*ry); atomicAdd(a+10, rx*rz); atomicAdd(a+11, ry*rz);
    atomicAdd(a+12, 1.0f);
}

__global__ __launch_bounds__(256) void frag_solve_fb(
    const float* __restrict__ acc, const int* __restrict__ frag_sizes,
    float* __restrict__ out, int n_frag)
{
    int f = blockIdx.x * blockDim.x + threadIdx.x;
    if (f >= n_frag) return;
    float a[13];
    #pragma unroll
    for (int k = 0; k < 13; ++k) a[k] = acc[(size_t)f * NACC + k];
    frag_epilogue(a, f, n_frag, frag_sizes, out);
}

extern "C" void kernel_launch(void* const* d_in, const int* in_sizes, int n_in,
                              void* d_out, int out_size, void* d_ws, size_t ws_size,
                              hipStream_t stream) {
    const float* f_atom     = (const float*)d_in[0];
    const float* atom_pos   = (const float*)d_in[1];
    const float* T_frag     = (const float*)d_in[2];
    const int*   frag_id    = (const int*)d_in[3];
    const int*   frag_sizes = (const int*)d_in[4];
    int n_atom = in_sizes[0] / 3;
    int n_frag = in_sizes[2] / 3;
    float* out = (float*)d_out;

    int nblk = (n_atom + APB - 1) / APB;          // 977
    int nbk  = (n_frag + FPB - 1) / FPB;          // 500

    size_t cur_bytes = (size_t)(NBK + 1) * sizeof(unsigned);
    size_t rec6_off  = (cur_bytes + 255) & ~(size_t)255;
    size_t rec6_bytes = (size_t)nbk * BCAP * 6 * sizeof(float);       // ~108 MB
    size_t lfs_off   = (rec6_off + rec6_bytes + 255) & ~(size_t)255;
    size_t need      = lfs_off + (size_t)nbk * BCAP * sizeof(unsigned short); // ~117 MB

    if (ws_size >= need && nbk <= NBK && nbk == 500 && (n_atom % 4) == 0) {
        unsigned*       cursor = (unsigned*)d_ws;
        float*          rec6   = (float*)((char*)d_ws + rec6_off);
        unsigned short* lfs    = (unsigned short*)((char*)d_ws + lfs_off);

        init_cursors<<<(NBK + 256) / 256, 256, 0, stream>>>(cursor, nbk);
        scatter_atoms<<<nblk, 512, 0, stream>>>(
            f_atom, atom_pos, frag_id, T_frag, cursor, rec6, lfs, n_atom);
        sort_reduce<<<nbk, 512, 0, stream>>>(
            rec6, lfs, cursor, frag_sizes, out, n_frag);
    } else {
        float* acc = (float*)d_ws;
        hipMemsetAsync(acc, 0, (size_t)n_frag * NACC * sizeof(float), stream);
        atom_scatter_fb<<<(n_atom + 255) / 256, 256, 0, stream>>>(
            f_atom, atom_pos, T_frag, frag_id, acc, n_atom);
        frag_solve_fb<<<(n_frag + 255) / 256, 256, 0, stream>>>(acc, frag_sizes, out, n_frag);
    }
}

// Round 12
// 224.903 us; speedup vs baseline: 1.1166x; 1.1166x over previous
//
#include <hip/hip_runtime.h>
#include <math.h>

// ===========================================================================
// Shared epilogue: 3x3 symmetric Jacobi eigensolve (double) + output writes.
// acc layout (13 floats): [0..2]=sum f  [3..5]=sum r x f
//                         [6..11]=sum rr^T (xx,yy,zz,xy,xz,yz)  [12]=count
// ===========================================================================
__device__ __forceinline__ void frag_epilogue(
    const float* a, int f, int n_frag, const int* __restrict__ frag_sizes,
    float* __restrict__ out)
{
    float cntf  = a[12];
    float denom = fmaxf(cntf, 1.0f);
    float vfx = a[0] / denom, vfy = a[1] / denom, vfz = a[2] / denom;

    double tq0 = (double)a[3], tq1 = (double)a[4], tq2 = (double)a[5];
    double Mxx = (double)a[6], Myy = (double)a[7], Mzz = (double)a[8];
    double Mxy = (double)a[9], Mxz = (double)a[10], Myz = (double)a[11];
    double tr = Mxx + Myy + Mzz;

    double A[3][3] = {
        { tr - Mxx, -Mxy,     -Mxz     },
        { -Mxy,     tr - Myy, -Myz     },
        { -Mxz,     -Myz,     tr - Mzz }
    };
    double V[3][3] = {{1,0,0},{0,1,0},{0,0,1}};

    for (int sweep = 0; sweep < 6; ++sweep) {
        for (int pq = 0; pq < 3; ++pq) {
            int p = (pq == 2) ? 1 : 0;
            int q = (pq == 0) ? 1 : 2;
            double apq = A[p][q];
            if (fabs(apq) <= 1e-14 * (fabs(A[p][p]) + fabs(A[q][q])) ||
                fabs(apq) < 1e-300) continue;
            double theta = (A[q][q] - A[p][p]) / (2.0 * apq);
            double tt;
            if (fabs(theta) > 1e100) tt = 1.0 / (2.0 * theta);
            else tt = copysign(1.0, theta) / (fabs(theta) + sqrt(theta * theta + 1.0));
            double c = 1.0 / sqrt(tt * tt + 1.0);
            double s = tt * c;
            double app = A[p][p], aqq = A[q][q];
            A[p][p] = app - tt * apq;
            A[q][q] = aqq + tt * apq;
            A[p][q] = 0.0; A[q][p] = 0.0;
            int r = 3 - p - q;
            double arp = A[r][p], arq = A[r][q];
            A[r][p] = c * arp - s * arq; A[p][r] = A[r][p];
            A[r][q] = s * arp + c * arq; A[q][r] = A[r][q];
            for (int i2 = 0; i2 < 3; ++i2) {
                double vip = V[i2][p], viq = V[i2][q];
                V[i2][p] = c * vip - s * viq;
                V[i2][q] = s * vip + c * viq;
            }
        }
    }

    double lam0 = A[0][0], lam1 = A[1][1], lam2 = A[2][2];
    double maxeig = fmax(fmax(fmax(lam0, lam1), lam2), 1e-8);
    double thr = 0.01 * maxeig;
    bool small_frag = (frag_sizes[f] <= 1);
    double o0 = (!small_frag && lam0 > thr) ? 1.0 : 0.0;
    double o1 = (!small_frag && lam1 > thr) ? 1.0 : 0.0;
    double o2 = (!small_frag && lam2 > thr) ? 1.0 : 0.0;

    double te0 = V[0][0]*tq0 + V[1][0]*tq1 + V[2][0]*tq2;
    double te1 = V[0][1]*tq0 + V[1][1]*tq1 + V[2][1]*tq2;
    double te2 = V[0][2]*tq0 + V[1][2]*tq1 + V[2][2]*tq2;
    double we0 = te0 / fmax(lam0, 1e-6) * o0;
    double we1 = te1 / fmax(lam1, 1e-6) * o1;
    double we2 = te2 / fmax(lam2, 1e-6) * o2;
    double w0 = V[0][0]*we0 + V[0][1]*we1 + V[0][2]*we2;
    double w1 = V[1][0]*we0 + V[1][1]*we1 + V[1][2]*we2;
    double w2 = V[2][0]*we0 + V[2][1]*we1 + V[2][2]*we2;

    size_t F = (size_t)n_frag;
    out[(size_t)f*3 + 0] = vfx;
    out[(size_t)f*3 + 1] = vfy;
    out[(size_t)f*3 + 2] = vfz;
    out[F*3 + (size_t)f*3 + 0] = (float)w0;
    out[F*3 + (size_t)f*3 + 1] = (float)w1;
    out[F*3 + (size_t)f*3 + 2] = (float)w2;

    float* P = out + F*6 + (size_t)f*9;
    #pragma unroll
    for (int i2 = 0; i2 < 3; ++i2)
        #pragma unroll
        for (int k = 0; k < 3; ++k)
            P[i2*3 + k] = (float)(V[i2][0]*o0*V[k][0] + V[i2][1]*o1*V[k][1]
                                  + V[i2][2]*o2*V[k][2]);
}

// ===========================================================================
// FAST PATH (round 19 = exact round-10 revert, the 226.35 us best).
// Round-11 lesson: 24-B records misalign with 64-B lines -> partial-line
// read-modify-write (FETCH 55->110 MB). 32-B (half-line) records are the
// minimum alignment-safe quantum for scattered streams. All scatter levers
// (run length >128B, occupancy, byte shrink) falsified at counter level;
// 2.4 TB/s scattered-line rate is the DRAM floor for this pattern.
// ===========================================================================
#define NBK  512             // bucket slots (used: nbk = ceil(F/400) = 500)
#define FPB  400             // fragments per bucket (500*400 = 200,000 exact)
#define BCAP 9000            // record capacity per bucket region
#define CAP2 1024            // LDS sort chunk capacity (records) in sort_reduce
#define MAXPT 2              // CAP2 / 512
#define TILE 16
#define APB  (256 * TILE)    // 4096 atoms per scatter block
#define SCHUNK 2048          // scatter LDS-sort chunk (atoms)
#define CPT    4             // SCHUNK / 512
#define RECMAX (500u * BCAP) // total record slots (nbk * BCAP)

__global__ __launch_bounds__(256) void init_cursors(
    unsigned* __restrict__ cursor, int nbk)
{
    int b = blockIdx.x * 256 + threadIdx.x;
    if (b <= nbk) cursor[b] = (unsigned)b * BCAP;
}

// Scatter with per-chunk LDS counting sort -> linear (segment-coalesced)
// global write-out into atomically reserved per-bucket windows.
// 512 threads: 2 blocks/CU x 8 waves = 16 waves/CU of store issue.
__global__ __launch_bounds__(512) void scatter_atoms(
    const float* __restrict__ f_atom,
    const float* __restrict__ atom_pos,
    const int*   __restrict__ frag_id,
    unsigned*    __restrict__ cursor,
    float4*      __restrict__ recs,
    int n_atom)
{
    __shared__ float    srt[SCHUNK * 7];  // 57,344 B staging
    __shared__ unsigned hist[NBK];        // per-chunk bucket counts
    __shared__ unsigned cbase[NBK];       // per-chunk exclusive bucket offsets
    __shared__ unsigned obase[NBK];       // reserved global window per bucket
    __shared__ unsigned wsum[4];
    int t = threadIdx.x;
    int lane = t & 63, w = t >> 6;

    for (int b = t; b < NBK; b += 512) hist[b] = 0;
    __syncthreads();

    const int4*   fid4 = (const int4*)frag_id;
    const float4* pos4 = (const float4*)atom_pos;
    const float4* ff4  = (const float4*)f_atom;
    int bs = blockIdx.x * APB;

    for (int c = 0; c < APB / SCHUNK; ++c) {
        int cs = bs + c * SCHUNK;
        int mchunk = n_atom - cs;
        if (mchunk > SCHUNK) mchunk = SCHUNK;
        if (mchunk < 0) mchunk = 0;

        // --- load + rank (4 atoms/thread = 1 int4 group) ---
        int      bkv[CPT], lfv[CPT];
        unsigned rk[CPT];
        float ax[CPT], ay[CPT], az[CPT], gx[CPT], gy[CPT], gz[CPT];
        {
            int i4 = (cs >> 2) + t;
            if (4 * i4 < n_atom) {
                int4 v = fid4[i4];
                float4 p0 = pos4[3*(size_t)i4+0], p1 = pos4[3*(size_t)i4+1], p2 = pos4[3*(size_t)i4+2];
                float4 g0 = ff4[3*(size_t)i4+0],  g1 = ff4[3*(size_t)i4+1],  g2 = ff4[3*(size_t)i4+2];
                int   fid_[4] = {v.x, v.y, v.z, v.w};
                float px_[4] = {p0.x, p0.w, p1.z, p2.y};
                float py_[4] = {p0.y, p1.x, p1.w, p2.z};
                float pz_[4] = {p0.z, p1.y, p2.x, p2.w};
                float gx_[4] = {g0.x, g0.w, g1.z, g2.y};
                float gy_[4] = {g0.y, g1.x, g1.w, g2.z};
                float gz_[4] = {g0.z, g1.y, g2.x, g2.w};
                #pragma unroll
                for (int cc = 0; cc < 4; ++cc) {
                    int fid = fid_[cc];
                    int bk = fid / FPB;
                    bkv[cc] = bk;
                    lfv[cc] = fid - bk * FPB;
                    rk[cc]  = atomicAdd(&hist[bk], 1u);
                    ax[cc] = px_[cc]; ay[cc] = py_[cc]; az[cc] = pz_[cc];
                    gx[cc] = gx_[cc]; gy[cc] = gy_[cc]; gz[cc] = gz_[cc];
                }
            } else {
                #pragma unroll
                for (int cc = 0; cc < 4; ++cc) bkv[cc] = -1;
            }
        }
        __syncthreads();

        // --- reserve global windows (1 atomicAdd per nonzero bucket) ---
        for (int b = t; b < NBK; b += 512) {
            unsigned cnt = hist[b];
            obase[b] = cnt ? atomicAdd(&cursor[b], cnt) : 0u;
        }

        // --- exclusive scan of hist[512] via wave shfl (256 pairs, waves 0-3) ---
        unsigned pv = 0, incl = 0;
        if (t < 256) {
            pv = hist[2*t] + hist[2*t + 1];
            incl = pv;
        }
        if (w < 4) {
            #pragma unroll
            for (int st = 1; st < 64; st <<= 1) {
                unsigned v = __shfl_up(incl, (unsigned)st, 64);
                if (lane >= st) incl += v;
            }
            if (lane == 63) wsum[w] = incl;
        }
        __syncthreads();
        if (t == 0) {
            unsigned cum = 0;
            #pragma unroll
            for (int k = 0; k < 4; ++k) { unsigned v = wsum[k]; wsum[k] = cum; cum += v; }
        }
        __syncthreads();
        if (t < 256) {
            unsigned excl = incl - pv + wsum[w];
            cbase[2*t]     = excl;
            cbase[2*t + 1] = excl + hist[2*t];
        }
        __syncthreads();

        // --- scatter into LDS in bucket-sorted order ---
        #pragma unroll
        for (int k = 0; k < CPT; ++k) {
            if (bkv[k] >= 0) {
                unsigned p = (cbase[bkv[k]] + rk[k]) * 7u;
                srt[p+0] = ax[k]; srt[p+1] = ay[k]; srt[p+2] = az[k];
                srt[p+3] = gx[k]; srt[p+4] = gy[k]; srt[p+5] = gz[k];
                srt[p+6] = __int_as_float(lfv[k] | (bkv[k] << 16));
            }
        }
        __syncthreads();

        // --- linear write-out: consecutive j -> runs of ~4 recs (128 B) ---
        #pragma unroll
        for (int k = 0; k < CPT; ++k) {
            int j = t + k * 512;
            if (j < mchunk) {
                const float* d = &srt[(unsigned)j * 7u];
                int pk = __float_as_int(d[6]);
                int lf = pk & 0xFFFF;
                int bk = pk >> 16;
                unsigned addr = obase[bk] + (unsigned)j - cbase[bk];
                if (addr < RECMAX) {   // OOB guard: cannot fault even on overflow
                    recs[2*(size_t)addr + 0] = make_float4(d[0], d[1], d[2], __int_as_float(lf));
                    recs[2*(size_t)addr + 1] = make_float4(d[3], d[4], d[5], 0.0f);
                }
            }
        }
        __syncthreads();

        // --- zero hist for next chunk ---
        for (int b = t; b < NBK; b += 512) hist[b] = 0;
        __syncthreads();
    }
}

// Counting-sort reduce: 512 threads, CAP2=1024, wave-shfl scan,
// 1 thread per fragment walk. 1 LDS atomic per record (rank only).
__global__ __launch_bounds__(512) void sort_reduce(
    const float4*   __restrict__ recs,
    const unsigned* __restrict__ cursor,
    const float*    __restrict__ T_frag,
    const int*      __restrict__ frag_sizes,
    float*          __restrict__ out,
    int n_frag)
{
    __shared__ float    srt[CAP2 * 7];   // 28,672 B
    __shared__ unsigned hist[FPB];       // 1600 B
    __shared__ unsigned cbase[FPB];      // 1600 B
    __shared__ unsigned wsum[8];

    int b = blockIdx.x, t = threadIdx.x;
    int lane = t & 63, w = t >> 6;
    int frag0 = b * FPB;
    int nf = n_frag - frag0;
    if (nf > FPB) nf = FPB;

    unsigned start = (unsigned)b * BCAP;
    unsigned end   = cursor[b];
    // clamp against pathological overflow (defensive, matches scatter guard)
    unsigned cap = (unsigned)(b + 1) * BCAP;
    if (end > cap) end = cap;

    bool own = (t < nf);
    float Tx = 0, Ty = 0, Tz = 0;
    if (own) {
        int f = frag0 + t;
        Tx = T_frag[3*f+0]; Ty = T_frag[3*f+1]; Tz = T_frag[3*f+2];
    }
    float s[12];
    #pragma unroll
    for (int k = 0; k < 12; ++k) s[k] = 0.0f;
    unsigned fragcnt = 0;

    for (unsigned c0 = start; c0 < end; c0 += CAP2) {
        unsigned m = end - c0;
        if (m > CAP2) m = CAP2;

        for (int k = t; k < FPB; k += 512) hist[k] = 0;
        __syncthreads();

        // --- load + rank ---
        float4 rv[MAXPT], fvv[MAXPT];
        int rlf[MAXPT];
        unsigned rrk[MAXPT];
        #pragma unroll
        for (int k = 0; k < MAXPT; ++k) {
            unsigned i = (unsigned)t + (unsigned)k * 512u;
            rlf[k] = -1;
            if (i < m) {
                rv[k]  = recs[2 * (size_t)(c0 + i) + 0];
                fvv[k] = recs[2 * (size_t)(c0 + i) + 1];
                int lf = __float_as_int(rv[k].w);
                rlf[k] = lf;
                rrk[k] = atomicAdd(&hist[lf], 1u);
            }
        }
        __syncthreads();

        // --- exclusive scan of hist[400] via wave shfl (pairs in waves 0..3) ---
        unsigned p = 0;
        if (t < FPB / 2) p = hist[2*t] + hist[2*t + 1];
        unsigned incl = p;
        if (w < 4) {
            #pragma unroll
            for (int st = 1; st < 64; st <<= 1) {
                unsigned v = __shfl_up(incl, (unsigned)st, 64);
                if (lane >= st) incl += v;
            }
            if (lane == 63) wsum[w] = incl;
        }
        __syncthreads();
        if (t == 0) {
            unsigned c = 0;
            #pragma unroll
            for (int k = 0; k < 4; ++k) { unsigned v = wsum[k]; wsum[k] = c; c += v; }
        }
        __syncthreads();
        if (t < FPB / 2) {
            unsigned excl = incl - p + wsum[w];
            cbase[2*t]     = excl;
            cbase[2*t + 1] = excl + hist[2*t];
        }
        __syncthreads();

        // --- scatter into LDS in fragment-sorted order (stride 7) ---
        #pragma unroll
        for (int k = 0; k < MAXPT; ++k) {
            if (rlf[k] >= 0) {
                unsigned q = (cbase[rlf[k]] + rrk[k]) * 7u;
                srt[q + 0] = rv[k].x;  srt[q + 1] = rv[k].y;  srt[q + 2] = rv[k].z;
                srt[q + 3] = fvv[k].x; srt[q + 4] = fvv[k].y; srt[q + 5] = fvv[k].z;
            }
        }
        __syncthreads();

        // --- per-fragment serial walk (1 thread/frag) ---
        if (own) {
            unsigned cb = cbase[t], cnt = hist[t];
            fragcnt += cnt;
            for (unsigned k = 0; k < cnt; ++k) {
                const float* d = &srt[(cb + k) * 7u];
                float rx = d[0] - Tx, ry = d[1] - Ty, rz = d[2] - Tz;
                float Fx = d[3], Fy = d[4], Fz = d[5];
                s[0] += Fx; s[1] += Fy; s[2] += Fz;
                s[3] += ry*Fz - rz*Fy;
                s[4] += rz*Fx - rx*Fz;
                s[5] += rx*Fy - ry*Fx;
                s[6] += rx*rx; s[7] += ry*ry; s[8] += rz*rz;
                s[9] += rx*ry; s[10] += rx*rz; s[11] += ry*rz;
            }
        }
        __syncthreads();
    }

    if (own) {
        float a[13];
        #pragma unroll
        for (int k = 0; k < 12; ++k) a[k] = s[k];
        a[12] = (float)fragcnt;
        frag_epilogue(a, frag0 + t, n_frag, frag_sizes, out);
    }
}

// ===========================================================================
// FALLBACK: direct global f32 atomics (round-1, correctness-safe, any ws)
// ===========================================================================
#define NACC 16

__global__ __launch_bounds__(256) void atom_scatter_fb(
    const float* __restrict__ f_atom, const float* __restrict__ atom_pos,
    const float* __restrict__ T_frag, const int* __restrict__ frag_id,
    float* __restrict__ acc, int n_atom)
{
    int i = blockIdx.x * blockDim.x + threadIdx.x;
    if (i >= n_atom) return;
    int fid = frag_id[i];
    float fx = f_atom[3*i+0], fy = f_atom[3*i+1], fz = f_atom[3*i+2];
    float px = atom_pos[3*i+0], py = atom_pos[3*i+1], pz = atom_pos[3*i+2];
    float rx = px - T_frag[3*fid+0], ry = py - T_frag[3*fid+1], rz = pz - T_frag[3*fid+2];
    float cx = ry*fz - rz*fy, cy = rz*fx - rx*fz, cz = rx*fy - ry*fx;
    float* a = acc + (size_t)fid * NACC;
    atomicAdd(a+0, fx);    atomicAdd(a+1, fy);    atomicAdd(a+2, fz);
    atomicAdd(a+3, cx);    atomicAdd(a+4, cy);    atomicAdd(a+5, cz);
    atomicAdd(a+6, rx*rx); atomicAdd(a+7, ry*ry); atomicAdd(a+8, rz*rz);
    atomicAdd(a+9, rx*ry); atomicAdd(a+10, rx*rz); atomicAdd(a+11, ry*rz);
    atomicAdd(a+12, 1.0f);
}

__global__ __launch_bounds__(256) void frag_solve_fb(
    const float* __restrict__ acc, const int* __restrict__ frag_sizes,
    float* __restrict__ out, int n_frag)
{
    int f = blockIdx.x * blockDim.x + threadIdx.x;
    if (f >= n_frag) return;
    float a[13];
    #pragma unroll
    for (int k = 0; k < 13; ++k) a[k] = acc[(size_t)f * NACC + k];
    frag_epilogue(a, f, n_frag, frag_sizes, out);
}

extern "C" void kernel_launch(void* const* d_in, const int* in_sizes, int n_in,
                              void* d_out, int out_size, void* d_ws, size_t ws_size,
                              hipStream_t stream) {
    const float* f_atom     = (const float*)d_in[0];
    const float* atom_pos   = (const float*)d_in[1];
    const float* T_frag     = (const float*)d_in[2];
    const int*   frag_id    = (const int*)d_in[3];
    const int*   frag_sizes = (const int*)d_in[4];
    int n_atom = in_sizes[0] / 3;
    int n_frag = in_sizes[2] / 3;
    float* out = (float*)d_out;

    int nblk = (n_atom + APB - 1) / APB;          // 977
    int nbk  = (n_frag + FPB - 1) / FPB;          // 500

    size_t cur_bytes = (size_t)(NBK + 1) * sizeof(unsigned);
    size_t recs_off  = (cur_bytes + 255) & ~(size_t)255;
    size_t need      = recs_off + (size_t)nbk * BCAP * 2 * sizeof(float4);  // ~144.05 MB

    if (ws_size >= need && nbk <= NBK && nbk == 500 && (n_atom % 4) == 0) {
        unsigned* cursor = (unsigned*)d_ws;
        float4*   recs   = (float4*)((char*)d_ws + recs_off);

        init_cursors<<<(NBK + 256) / 256, 256, 0, stream>>>(cursor, nbk);
        scatter_atoms<<<nblk, 512, 0, stream>>>(
            f_atom, atom_pos, frag_id, cursor, recs, n_atom);
        sort_reduce<<<nbk, 512, 0, stream>>>(
            recs, cursor, T_frag, frag_sizes, out, n_frag);
    } else {
        float* acc = (float*)d_ws;
        hipMemsetAsync(acc, 0, (size_t)n_frag * NACC * sizeof(float), stream);
        atom_scatter_fb<<<(n_atom + 255) / 256, 256, 0, stream>>>(
            f_atom, atom_pos, T_frag, frag_id, acc, n_atom);
        frag_solve_fb<<<(n_frag + 255) / 256, 256, 0, stream>>>(acc, frag_sizes, out, n_frag);
    }
}